// Round 5
// baseline (400.407 us; speedup 1.0000x reference)
//
#include <hip/hip_runtime.h>
#include <math.h>

#define Bq 2
#define Lq 2048
#define DIMq 768
#define NHq 12
#define HDq 64
#define LOG2E 1.44269504f
#define NSPLIT 2
#define KT_PER_SPLIT (Lq / 64 / NSPLIT)   // 16

typedef __attribute__((ext_vector_type(8))) short short8;
typedef __attribute__((ext_vector_type(4))) short short4v;
typedef __attribute__((ext_vector_type(4))) float float4v;

typedef __attribute__((address_space(3))) unsigned int as3_u32;
typedef __attribute__((address_space(1))) unsigned int as1_u32;

static __device__ __forceinline__ short f2bf(float f) {
    union { float f; unsigned u; } v; v.f = f;
    unsigned r = (v.u + 0x7FFF + ((v.u >> 16) & 1)) >> 16;   // RNE
    return (short)r;
}

// async global->LDS, 16B per lane (wave-uniform LDS base + lane*16)
static __device__ __forceinline__ void gld_lds16(const short* g, short* l) {
    __builtin_amdgcn_global_load_lds((const as1_u32*)g, (as3_u32*)l, 16, 0, 0);
}

// ---------------------------------------------------------------------------
// fp32 -> bf16 conversion for x and the four weight matrices.
// ---------------------------------------------------------------------------
__global__ __launch_bounds__(256)
void to_bf16(const float* __restrict__ x,  const float* __restrict__ wq,
             const float* __restrict__ wk, const float* __restrict__ wv,
             const float* __restrict__ wo,
             short* __restrict__ xb, short* __restrict__ wqb,
             short* __restrict__ wkb, short* __restrict__ wvb,
             short* __restrict__ wob)
{
    int blk = blockIdx.x;
    const float* s; short* d; int off;
    if      (blk <  768) { s = x;  d = xb;  off = blk * 1024; }
    else if (blk <  912) { s = wq; d = wqb; off = (blk -  768) * 1024; }
    else if (blk < 1056) { s = wk; d = wkb; off = (blk -  912) * 1024; }
    else if (blk < 1200) { s = wv; d = wvb; off = (blk - 1056) * 1024; }
    else                 { s = wo; d = wob; off = (blk - 1200) * 1024; }
    const float4* s4 = (const float4*)s;
    short4v* d4 = (short4v*)d;
#pragma unroll
    for (int i = 0; i < 4; ++i) {
        int idx = off + threadIdx.x + i * 256;
        float4 v = s4[idx];
        short4v o;
        o[0] = f2bf(v.x); o[1] = f2bf(v.y); o[2] = f2bf(v.z); o[3] = f2bf(v.w);
        d4[idx] = o;
    }
}

// ---------------------------------------------------------------------------
// bf16 MFMA GEMM (m97 structure): C = A @ W^T. 128x128 tile, BK=64, 256 thr =
// 4 waves in 2x2; each wave computes 64x64 via 4x4 16x16x32 frags. Staging via
// global_load_lds width 16 into linear LDS; 2 barriers per K-step.
// mode 1: write bf16 split-head [B][NH][L][HD]; mode 0: fp32 flat [M][768].
// ---------------------------------------------------------------------------
__global__ __launch_bounds__(256, 2)
void gemm_bf16(const short* __restrict__ A,
               const short* __restrict__ W0, const short* __restrict__ W1,
               const short* __restrict__ W2,
               short* __restrict__ D0, short* __restrict__ D1,
               short* __restrict__ D2, float* __restrict__ DF, int mode)
{
    const int z = blockIdx.z;
    const short* W = (z == 0) ? W0 : ((z == 1) ? W1 : W2);
    short* DH = (z == 0) ? D0 : ((z == 1) ? D1 : D2);

    __shared__ __align__(16) short As[128][64];   // linear: global_load_lds dst
    __shared__ __align__(16) short Ws[128][64];

    const int tid  = threadIdx.x;
    const int wave = tid >> 6;
    const int lane = tid & 63;
    const int col  = lane & 15;
    const int quad = lane >> 4;
    const int wr = wave >> 1, wc = wave & 1;
    const int m0 = blockIdx.y * 128, n0 = blockIdx.x * 128;

    float4v acc[4][4];
#pragma unroll
    for (int mt = 0; mt < 4; ++mt)
#pragma unroll
        for (int nt = 0; nt < 4; ++nt) acc[mt][nt] = (float4v){0.f, 0.f, 0.f, 0.f};

    const short* Ab = A + (size_t)m0 * DIMq;
    const short* Wb = W + (size_t)n0 * DIMq;

    for (int k0 = 0; k0 < DIMq; k0 += 64) {
        __syncthreads();                       // readers done with LDS
        // 128 rows x 64 cols x 2B = 16KB per tile = 1024 chunks of 16B
#pragma unroll
        for (int i = 0; i < 4; ++i) {
            int g = i * 256 + tid;             // chunk id; lane-linear per wave
            int row = g >> 3, ch = g & 7;
            gld_lds16(Ab + (size_t)row * DIMq + k0 + ch * 8, (short*)As + g * 8);
            gld_lds16(Wb + (size_t)row * DIMq + k0 + ch * 8, (short*)Ws + g * 8);
        }
        __syncthreads();                       // (compiler drains vmcnt here)
#pragma unroll
        for (int kk = 0; kk < 2; ++kk) {
            short8 a[4], bfr[4];
#pragma unroll
            for (int mt = 0; mt < 4; ++mt)
                a[mt] = *(const short8*)&As[wr * 64 + mt * 16 + col][kk * 32 + quad * 8];
#pragma unroll
            for (int nt = 0; nt < 4; ++nt)
                bfr[nt] = *(const short8*)&Ws[wc * 64 + nt * 16 + col][kk * 32 + quad * 8];
#pragma unroll
            for (int mt = 0; mt < 4; ++mt)
#pragma unroll
                for (int nt = 0; nt < 4; ++nt)
                    acc[mt][nt] = __builtin_amdgcn_mfma_f32_16x16x32_bf16(
                        a[mt], bfr[nt], acc[mt][nt], 0, 0, 0);
        }
    }

#pragma unroll
    for (int mt = 0; mt < 4; ++mt)
#pragma unroll
    for (int reg = 0; reg < 4; ++reg) {
        int m = m0 + wr * 64 + mt * 16 + quad * 4 + reg;
#pragma unroll
        for (int nt = 0; nt < 4; ++nt) {
            int n = n0 + wc * 64 + nt * 16 + col;
            if (mode == 1) {
                int b = m >> 11, l = m & 2047, h = n >> 6, c = n & 63;
                DH[(((size_t)(b * NHq + h)) * Lq + l) * HDq + c] = f2bf(acc[mt][nt][reg]);
            } else {
                DF[(size_t)m * DIMq + n] = acc[mt][nt][reg];
            }
        }
    }
}

// ---------------------------------------------------------------------------
// V transpose: [B][NH][L][HD] -> [B][NH][HD][L], once.
// ---------------------------------------------------------------------------
__global__ __launch_bounds__(256)
void transpose_v(const short* __restrict__ Vh, short* __restrict__ VT)
{
    const int lt = blockIdx.x;   // 0..31 (64-row L tile)
    const int bh = blockIdx.y;   // 0..23 (b*NH+h)
    const short* src = Vh + ((size_t)bh * Lq + lt * 64) * HDq;
    short* dst = VT + (size_t)bh * HDq * Lq + lt * 64;
    __shared__ __align__(16) short t[64][72];
    const int tid = threadIdx.x;
    {
        int row = tid & 63, seg = tid >> 6;          // seg: 16-col chunk
        *(short8*)&t[row][seg * 16]     = *(const short8*)&src[row * HDq + seg * 16];
        *(short8*)&t[row][seg * 16 + 8] = *(const short8*)&src[row * HDq + seg * 16 + 8];
    }
    __syncthreads();
    {
        int c = tid >> 2, seg = tid & 3;             // c: hd row, seg: 16-l chunk
        short8 o0, o1;
#pragma unroll
        for (int j = 0; j < 8; ++j) o0[j] = t[seg * 16 + j][c];
#pragma unroll
        for (int j = 0; j < 8; ++j) o1[j] = t[seg * 16 + 8 + j][c];
        *(short8*)&dst[(size_t)c * Lq + seg * 16]     = o0;
        *(short8*)&dst[(size_t)c * Lq + seg * 16 + 8] = o1;
    }
}

// ---------------------------------------------------------------------------
// MFMA flash attention, no-max softmax, split-K (NSPLIT=2), 1 barrier/K-tile.
//  - XOR-swizzled unpadded LDS tiles (byte ^= (row&7)<<4): LDS = 40960 B
//    exactly -> 4 blocks/CU residency (was 46080 -> 3).
//  - each block covers 16 of 32 K-tiles; un-normalized O/l partials are
//    LINEAR, so splits just add. fp32 partials to workspace; combine_split
//    normalizes and emits bf16 AO.
//  - grid 1536 fills the 4th residency slot; XCD-chunked swizzle keeps
//    (s, b) siblings (sharing bias / K/V panels) on one XCD.
// ---------------------------------------------------------------------------
__global__ __launch_bounds__(256, 2)
void attn_fwd_mfma(const short* __restrict__ Qh, const short* __restrict__ Kh,
                   const short* __restrict__ VT, const float* __restrict__ pos_bias,
                   const int* __restrict__ mask,
                   float* __restrict__ Op, float* __restrict__ Lp)
{
    // 1536 blocks -> 8 XCD chunks of 192; logical = ((h*32+qt)*2 + b)*2 + s
    const int hw = blockIdx.x;
    const int logical = (hw & 7) * 192 + (hw >> 3);
    const int s  = logical & 1;
    const int b  = (logical >> 1) & 1;
    const int qt = (logical >> 2) & 31;
    const int h  = logical >> 7;

    const short* Q = Qh + ((size_t)(b * NHq + h)) * Lq * HDq;
    const short* K = Kh + ((size_t)(b * NHq + h)) * Lq * HDq;
    const short* V = VT + ((size_t)(b * NHq + h)) * HDq * Lq;   // [hd][L]
    const int* mk = mask + (size_t)b * Lq;

    __shared__ __align__(16) short Ks[2][64][64];  // [buf][key][hd], swizzled
    __shared__ __align__(16) short Vt[2][64][64];  // [buf][hd][key], swizzled
    __shared__ __align__(16) short Ps[64][64];     // [qrow][key],   swizzled

    const int tid  = threadIdx.x;
    const int wave = tid >> 6;
    const int lane = tid & 63;
    const int col  = lane & 15;
    const int quad = lane >> 4;

    const int ktbeg = s * KT_PER_SPLIT;
    const int ktend = ktbeg + KT_PER_SPLIT;

    // persistent Q A-frags
    short8 qa[2];
    {
        const short* qrow = Q + (size_t)(qt * 64 + wave * 16 + col) * HDq;
        qa[0] = *(const short8*)&qrow[quad * 8];
        qa[1] = *(const short8*)&qrow[32 + quad * 8];
    }

    const float* brow = pos_bias + (size_t)h * Lq * Lq
                      + (size_t)(qt * 64 + wave * 16 + quad * 4) * Lq + col;

    float bcur[4][4], bnxt[4][4];
    auto prefetch = [&](int kt, float (&bb)[4][4]) {
#pragma unroll
        for (int nt = 0; nt < 4; ++nt) {
            int mval = mk[kt * 64 + col + 16 * nt];
            float fm = (mval == 0) ? -1e30f : 0.0f;
#pragma unroll
            for (int reg = 0; reg < 4; ++reg)
                bb[nt][reg] = (brow[(size_t)reg * Lq + kt * 64 + 16 * nt] + fm) * LOG2E;
        }
    };

    // K/V register staging; LDS writes XOR-swizzled: byte ^= (row&7)<<4
    short8 kreg[2], vreg[2];
    auto loadKV = [&](int kt) {
        const short* Kt = K + (size_t)kt * 64 * HDq;
#pragma unroll
        for (int i = 0; i < 2; ++i) {
            int idx = tid + i * 256;
            kreg[i] = *(const short8*)&Kt[(idx >> 3) * HDq + (idx & 7) * 8];
            vreg[i] = *(const short8*)&V[(size_t)(idx >> 3) * Lq + kt * 64 + (idx & 7) * 8];
        }
    };
    auto writeKV = [&](int buf) {
#pragma unroll
        for (int i = 0; i < 2; ++i) {
            int idx = tid + i * 256;
            int row = idx >> 3;
            int ofs = ((idx & 7) * 16) ^ ((row & 7) << 4);
            *(short8*)((char*)&Ks[buf][0][0] + row * 128 + ofs) = kreg[i];
            *(short8*)((char*)&Vt[buf][0][0] + row * 128 + ofs) = vreg[i];
        }
    };

    float4v Oacc[4];
    float l_part[4];
#pragma unroll
    for (int nt = 0; nt < 4; ++nt) Oacc[nt] = (float4v){0.f, 0.f, 0.f, 0.f};
#pragma unroll
    for (int r = 0; r < 4; ++r) l_part[r] = 0.f;

    // prologue: first tile staged single-buffered
    loadKV(ktbeg);
    writeKV(0);
    prefetch(ktbeg, bcur);
    __syncthreads();

    int cur = 0;
    for (int kt = ktbeg; kt < ktend; ++kt) {
        const bool more = (kt + 1 < ktend);
        if (more) {            // issue next tile's global loads NOW
            loadKV(kt + 1);
            prefetch(kt + 1, bnxt);
        }

        // --- QK^T from Ks[cur] (swizzled read: row&7 == col&7) ---
        const int rofs = (col & 7) << 4;
        float4v S[4];
#pragma unroll
        for (int nt = 0; nt < 4; ++nt) S[nt] = (float4v){0.f, 0.f, 0.f, 0.f};
        __builtin_amdgcn_s_setprio(1);
#pragma unroll
        for (int kk = 0; kk < 2; ++kk) {
#pragma unroll
            for (int nt = 0; nt < 4; ++nt) {
                short8 bfr = *(const short8*)((const char*)&Ks[cur][0][0]
                              + (nt * 16 + col) * 128 + ((kk * 64 + quad * 16) ^ rofs));
                S[nt] = __builtin_amdgcn_mfma_f32_16x16x32_bf16(qa[kk], bfr, S[nt], 0, 0, 0);
            }
        }
        __builtin_amdgcn_s_setprio(0);

        // --- no-max softmax: p = exp2(S*log2e + b') ; deferred row-sum ---
#pragma unroll
        for (int nt = 0; nt < 4; ++nt)
#pragma unroll
            for (int reg = 0; reg < 4; ++reg) {
                float p = __builtin_amdgcn_exp2f(
                    __builtin_fmaf(S[nt][reg], LOG2E, bcur[nt][reg]));
                l_part[reg] += p;
                int prow = wave * 16 + quad * 4 + reg;
                *(short*)((char*)&Ps[0][0] + prow * 128
                          + (((col + 16 * nt) * 2) ^ ((prow & 7) << 4))) = f2bf(p);
            }
        // NO barrier: Ps write->read is intra-wave (same 16-row band);
        // Vt[cur]/Ks[cur] were made visible by last iteration's barrier.

        // --- PV from Ps, Vt[cur] ---
        __builtin_amdgcn_s_setprio(1);
#pragma unroll
        for (int kk = 0; kk < 2; ++kk) {
            short8 pa = *(const short8*)((const char*)&Ps[0][0]
                          + (wave * 16 + col) * 128 + ((kk * 64 + quad * 16) ^ rofs));
#pragma unroll
            for (int nt = 0; nt < 4; ++nt) {
                short8 vb = *(const short8*)((const char*)&Vt[cur][0][0]
                              + (nt * 16 + col) * 128 + ((kk * 64 + quad * 16) ^ rofs));
                Oacc[nt] = __builtin_amdgcn_mfma_f32_16x16x32_bf16(pa, vb, Oacc[nt], 0, 0, 0);
            }
        }
        __builtin_amdgcn_s_setprio(0);

        // --- write next tile into the other buffer (vmcnt wait on kreg/vreg) ---
        if (more) writeKV(cur ^ 1);
        __syncthreads();   // next buf visible; Ks/Vt[cur] reads done block-wide
        cur ^= 1;

#pragma unroll
        for (int nt = 0; nt < 4; ++nt)
#pragma unroll
            for (int reg = 0; reg < 4; ++reg)
                bcur[nt][reg] = bnxt[nt][reg];
    }

    // --- epilogue: reduce l across 16 col-lanes; store fp32 partials ---
    float l[4];
#pragma unroll
    for (int reg = 0; reg < 4; ++reg) {
        float v = l_part[reg];
#pragma unroll
        for (int off = 1; off < 16; off <<= 1)
            v += __shfl_xor(v, off, 64);
        l[reg] = v;
    }

    // O partial: [s][b][row][768] fp32, un-normalized
    float* orow = Op + (((size_t)(s * Bq + b)) * Lq + qt * 64 + wave * 16 + quad * 4) * DIMq
                + h * HDq + col;
#pragma unroll
    for (int reg = 0; reg < 4; ++reg)
#pragma unroll
        for (int nt = 0; nt < 4; ++nt)
            orow[(size_t)reg * DIMq + 16 * nt] = Oacc[nt][reg];

    if (col == 0) {
        float* lrow = Lp + (((size_t)(s * Bq + b)) * NHq + h) * Lq
                    + qt * 64 + wave * 16 + quad * 4;
#pragma unroll
        for (int reg = 0; reg < 4; ++reg) lrow[reg] = l[reg];
    }
}

// ---------------------------------------------------------------------------
// combine splits: AO[b][l][d] = (O0+O1)/(l0+l1), bf16 out.
// one float4 per thread; 786432 float4s total.
// ---------------------------------------------------------------------------
__global__ __launch_bounds__(256)
void combine_split(const float* __restrict__ Op, const float* __restrict__ Lp,
                   short* __restrict__ AO)
{
    const int idx = blockIdx.x * 256 + threadIdx.x;   // float4 id
    const int row = idx / (DIMq / 4);                 // b*Lq + l
    const int d4  = idx - row * (DIMq / 4);
    const int h   = d4 >> 4;                          // d4*4/64
    const int b   = row >> 11, l = row & 2047;

    const float4* O0 = (const float4*)Op;
    const float4* O1 = O0 + (size_t)Bq * Lq * (DIMq / 4);
    float l0 = Lp[((size_t)b * NHq + h) * Lq + l];
    float l1 = Lp[(((size_t)Bq + b) * NHq + h) * Lq + l];
    float inv = 1.0f / (l0 + l1);

    float4 a = O0[idx], c = O1[idx];
    short4v o;
    o[0] = f2bf((a.x + c.x) * inv);
    o[1] = f2bf((a.y + c.y) * inv);
    o[2] = f2bf((a.z + c.z) * inv);
    o[3] = f2bf((a.w + c.w) * inv);
    ((short4v*)AO)[idx] = o;
}

// ---------------------------------------------------------------------------
extern "C" void kernel_launch(void* const* d_in, const int* in_sizes, int n_in,
                              void* d_out, int out_size, void* d_ws, size_t ws_size,
                              hipStream_t stream) {
    const float* x        = (const float*)d_in[0];
    const float* pos_bias = (const float*)d_in[1];
    const float* Wq       = (const float*)d_in[2];
    const float* Wk       = (const float*)d_in[3];
    const float* Wv       = (const float*)d_in[4];
    const float* Wo       = (const float*)d_in[5];
    const int*   mask     = (const int*)d_in[6];
    float* out = (float*)d_out;

    const size_t nX = (size_t)Bq * Lq * DIMq;       // 3,145,728
    const size_t nW = (size_t)DIMq * DIMq;          //   589,824
    short* xb  = (short*)d_ws;
    short* wqb = xb  + nX;
    short* wkb = wqb + nW;
    short* wvb = wkb + nW;
    short* wob = wvb + nW;
    short* Qh  = wob + nW;
    short* Kh  = Qh  + nX;
    short* Vh  = Kh  + nX;
    short* AOb = Vh  + nX;
    float* Opf = (float*)(AOb + nX);                // 2 * nX fp32 partial O
    float* Lpf = Opf + (size_t)NSPLIT * nX;         // 2 * B*NH*L fp32 partial l
    short* VTb = xb;   // xb is dead after the QKV GEMM; reuse for V^T

    dim3 blk(256);
    hipLaunchKernelGGL(to_bf16, dim3(1344), blk, 0, stream,
                       x, Wq, Wk, Wv, Wo, xb, wqb, wkb, wvb, wob);

    // fused QKV projections, 128x128 tiles
    hipLaunchKernelGGL(gemm_bf16, dim3(DIMq / 128, (Bq * Lq) / 128, 3), blk, 0, stream,
                       xb, wqb, wkb, wvb, Qh, Kh, Vh, (float*)nullptr, 1);

    // V: [B][NH][L][HD] -> [B][NH][HD][L]
    hipLaunchKernelGGL(transpose_v, dim3(Lq / 64, Bq * NHq), blk, 0, stream,
                       Vh, VTb);

    hipLaunchKernelGGL(attn_fwd_mfma, dim3(Lq / 64 * NHq * Bq * NSPLIT), blk, 0, stream,
                       Qh, Kh, VTb, pos_bias, mask, Opf, Lpf);

    hipLaunchKernelGGL(combine_split, dim3(nX / 4 / 256), blk, 0, stream,
                       Opf, Lpf, AOb);

    // output projection, fp32 out
    hipLaunchKernelGGL(gemm_bf16, dim3(DIMq / 128, (Bq * Lq) / 128, 1), blk, 0, stream,
                       AOb, wob, wob, wob, (short*)nullptr, (short*)nullptr,
                       (short*)nullptr, out, 0);
}

// Round 6
// 384.148 us; speedup vs baseline: 1.0423x; 1.0423x over previous
//
#include <hip/hip_runtime.h>
#include <math.h>

#define Bq 2
#define Lq 2048
#define DIMq 768
#define NHq 12
#define HDq 64
#define LOG2E 1.44269504f

typedef __attribute__((ext_vector_type(8))) short short8;
typedef __attribute__((ext_vector_type(4))) short short4v;
typedef __attribute__((ext_vector_type(4))) float float4v;

typedef __attribute__((address_space(3))) unsigned int as3_u32;
typedef __attribute__((address_space(1))) unsigned int as1_u32;

static __device__ __forceinline__ short f2bf(float f) {
    union { float f; unsigned u; } v; v.f = f;
    unsigned r = (v.u + 0x7FFF + ((v.u >> 16) & 1)) >> 16;   // RNE
    return (short)r;
}

// async global->LDS, 16B per lane (wave-uniform LDS base + lane*16)
static __device__ __forceinline__ void gld_lds16(const short* g, short* l) {
    __builtin_amdgcn_global_load_lds((const as1_u32*)g, (as3_u32*)l, 16, 0, 0);
}

// ---------------------------------------------------------------------------
// fp32 -> bf16 conversion for x and the four weight matrices.
// ---------------------------------------------------------------------------
__global__ __launch_bounds__(256)
void to_bf16(const float* __restrict__ x,  const float* __restrict__ wq,
             const float* __restrict__ wk, const float* __restrict__ wv,
             const float* __restrict__ wo,
             short* __restrict__ xb, short* __restrict__ wqb,
             short* __restrict__ wkb, short* __restrict__ wvb,
             short* __restrict__ wob)
{
    int blk = blockIdx.x;
    const float* s; short* d; int off;
    if      (blk <  768) { s = x;  d = xb;  off = blk * 1024; }
    else if (blk <  912) { s = wq; d = wqb; off = (blk -  768) * 1024; }
    else if (blk < 1056) { s = wk; d = wkb; off = (blk -  912) * 1024; }
    else if (blk < 1200) { s = wv; d = wvb; off = (blk - 1056) * 1024; }
    else                 { s = wo; d = wob; off = (blk - 1200) * 1024; }
    const float4* s4 = (const float4*)s;
    short4v* d4 = (short4v*)d;
#pragma unroll
    for (int i = 0; i < 4; ++i) {
        int idx = off + threadIdx.x + i * 256;
        float4 v = s4[idx];
        short4v o;
        o[0] = f2bf(v.x); o[1] = f2bf(v.y); o[2] = f2bf(v.z); o[3] = f2bf(v.w);
        d4[idx] = o;
    }
}

// ---------------------------------------------------------------------------
// bf16 MFMA GEMM (m97 structure): C = A @ W^T. 128x128 tile, BK=64, 256 thr =
// 4 waves in 2x2; each wave computes 64x64 via 4x4 16x16x32 frags. Staging via
// global_load_lds width 16 into linear LDS; 2 barriers per K-step.
// mode 1: write bf16 split-head [B][NH][L][HD]; mode 0: fp32 flat [M][768].
// ---------------------------------------------------------------------------
__global__ __launch_bounds__(256, 2)
void gemm_bf16(const short* __restrict__ A,
               const short* __restrict__ W0, const short* __restrict__ W1,
               const short* __restrict__ W2,
               short* __restrict__ D0, short* __restrict__ D1,
               short* __restrict__ D2, float* __restrict__ DF, int mode)
{
    const int z = blockIdx.z;
    const short* W = (z == 0) ? W0 : ((z == 1) ? W1 : W2);
    short* DH = (z == 0) ? D0 : ((z == 1) ? D1 : D2);

    __shared__ __align__(16) short As[128][64];   // linear: global_load_lds dst
    __shared__ __align__(16) short Ws[128][64];

    const int tid  = threadIdx.x;
    const int wave = tid >> 6;
    const int lane = tid & 63;
    const int col  = lane & 15;
    const int quad = lane >> 4;
    const int wr = wave >> 1, wc = wave & 1;
    const int m0 = blockIdx.y * 128, n0 = blockIdx.x * 128;

    float4v acc[4][4];
#pragma unroll
    for (int mt = 0; mt < 4; ++mt)
#pragma unroll
        for (int nt = 0; nt < 4; ++nt) acc[mt][nt] = (float4v){0.f, 0.f, 0.f, 0.f};

    const short* Ab = A + (size_t)m0 * DIMq;
    const short* Wb = W + (size_t)n0 * DIMq;

    for (int k0 = 0; k0 < DIMq; k0 += 64) {
        __syncthreads();                       // readers done with LDS
        // 128 rows x 64 cols x 2B = 16KB per tile = 1024 chunks of 16B
#pragma unroll
        for (int i = 0; i < 4; ++i) {
            int g = i * 256 + tid;             // chunk id; lane-linear per wave
            int row = g >> 3, ch = g & 7;
            gld_lds16(Ab + (size_t)row * DIMq + k0 + ch * 8, (short*)As + g * 8);
            gld_lds16(Wb + (size_t)row * DIMq + k0 + ch * 8, (short*)Ws + g * 8);
        }
        __syncthreads();                       // (compiler drains vmcnt here)
#pragma unroll
        for (int kk = 0; kk < 2; ++kk) {
            short8 a[4], bfr[4];
#pragma unroll
            for (int mt = 0; mt < 4; ++mt)
                a[mt] = *(const short8*)&As[wr * 64 + mt * 16 + col][kk * 32 + quad * 8];
#pragma unroll
            for (int nt = 0; nt < 4; ++nt)
                bfr[nt] = *(const short8*)&Ws[wc * 64 + nt * 16 + col][kk * 32 + quad * 8];
#pragma unroll
            for (int mt = 0; mt < 4; ++mt)
#pragma unroll
                for (int nt = 0; nt < 4; ++nt)
                    acc[mt][nt] = __builtin_amdgcn_mfma_f32_16x16x32_bf16(
                        a[mt], bfr[nt], acc[mt][nt], 0, 0, 0);
        }
    }

#pragma unroll
    for (int mt = 0; mt < 4; ++mt)
#pragma unroll
    for (int reg = 0; reg < 4; ++reg) {
        int m = m0 + wr * 64 + mt * 16 + quad * 4 + reg;
#pragma unroll
        for (int nt = 0; nt < 4; ++nt) {
            int n = n0 + wc * 64 + nt * 16 + col;
            if (mode == 1) {
                int b = m >> 11, l = m & 2047, h = n >> 6, c = n & 63;
                DH[(((size_t)(b * NHq + h)) * Lq + l) * HDq + c] = f2bf(acc[mt][nt][reg]);
            } else {
                DF[(size_t)m * DIMq + n] = acc[mt][nt][reg];
            }
        }
    }
}

// ---------------------------------------------------------------------------
// V transpose: [B][NH][L][HD] -> [B][NH][HD][L], once.
// ---------------------------------------------------------------------------
__global__ __launch_bounds__(256)
void transpose_v(const short* __restrict__ Vh, short* __restrict__ VT)
{
    const int lt = blockIdx.x;   // 0..31 (64-row L tile)
    const int bh = blockIdx.y;   // 0..23 (b*NH+h)
    const short* src = Vh + ((size_t)bh * Lq + lt * 64) * HDq;
    short* dst = VT + (size_t)bh * HDq * Lq + lt * 64;
    __shared__ __align__(16) short t[64][72];
    const int tid = threadIdx.x;
    {
        int row = tid & 63, seg = tid >> 6;          // seg: 16-col chunk
        *(short8*)&t[row][seg * 16]     = *(const short8*)&src[row * HDq + seg * 16];
        *(short8*)&t[row][seg * 16 + 8] = *(const short8*)&src[row * HDq + seg * 16 + 8];
    }
    __syncthreads();
    {
        int c = tid >> 2, seg = tid & 3;             // c: hd row, seg: 16-l chunk
        short8 o0, o1;
#pragma unroll
        for (int j = 0; j < 8; ++j) o0[j] = t[seg * 16 + j][c];
#pragma unroll
        for (int j = 0; j < 8; ++j) o1[j] = t[seg * 16 + 8 + j][c];
        *(short8*)&dst[(size_t)c * Lq + seg * 16]     = o0;
        *(short8*)&dst[(size_t)c * Lq + seg * 16 + 8] = o1;
    }
}

// ---------------------------------------------------------------------------
// MFMA flash attention, no-max softmax, 8-wave key-split blocks (512 thr):
//  - wave (wrow = w>>1, wkey = w&1): q-rows [wrow*16,+16), key-half
//    [wkey*32,+32) for QK/softmax; output d-half [wkey*32,+32) for PV.
//  - un-normalized softmax is LINEAR in keys -> no per-tile cross-wave
//    reduction; per-wave partial l, one LDS exchange in the epilogue.
//  - per-wave serial chain per tile: 4 QK MFMA + 8 exp + 4 PV MFMA (half of
//    the 4-wave version), at 24 waves/CU (was 12) for latency hiding.
//  - 2 barriers/tile: P-visibility (cross-wave PV) and buffer rotation.
//  - padded [64][72] LDS (known conflict-free); K/V reg-staged dbuf.
// ---------------------------------------------------------------------------
__global__ __launch_bounds__(512, 6)
void attn_fwd_mfma(const short* __restrict__ Qh, const short* __restrict__ Kh,
                   const short* __restrict__ VT, const float* __restrict__ pos_bias,
                   const int* __restrict__ mask, short* __restrict__ AO)
{
    // hw block -> XCD chunk of 96 consecutive logicals; logical = (h*32+qt)*2+b
    const int hw = blockIdx.x;                     // 0..767
    const int logical = (hw & 7) * 96 + (hw >> 3);
    const int b  = logical & 1;
    const int qt = (logical >> 1) & 31;
    const int h  = logical >> 6;

    const short* Q = Qh + ((size_t)(b * NHq + h)) * Lq * HDq;
    const short* K = Kh + ((size_t)(b * NHq + h)) * Lq * HDq;
    const short* V = VT + ((size_t)(b * NHq + h)) * HDq * Lq;   // [hd][L]
    const int* mk = mask + (size_t)b * Lq;

    __shared__ __align__(16) short Ks[2][64][72];  // [buf][key][hd]
    __shared__ __align__(16) short Vt[2][64][72];  // [buf][hd][key]
    __shared__ __align__(16) short Ps[64][72];     // [qrow][key]
    __shared__ float lbuf[8][16];                  // per-wave row l partials

    const int tid  = threadIdx.x;
    const int wave = tid >> 6;        // 0..7
    const int lane = tid & 63;
    const int col  = lane & 15;
    const int quad = lane >> 4;
    const int wrow = wave >> 1;       // 0..3: q-row band
    const int wkey = wave & 1;        // 0..1: key/d half

    // persistent Q A-frags (rows wrow*16 + col)
    short8 qa[2];
    {
        const short* qrow = Q + (size_t)(qt * 64 + wrow * 16 + col) * HDq;
        qa[0] = *(const short8*)&qrow[quad * 8];
        qa[1] = *(const short8*)&qrow[32 + quad * 8];
    }

    const float* brow = pos_bias + (size_t)h * Lq * Lq
                      + (size_t)(qt * 64 + wrow * 16 + quad * 4) * Lq + col;

    float bcur[2][4], bnxt[2][4];
    auto prefetch = [&](int kt, float (&bb)[2][4]) {
#pragma unroll
        for (int ntl = 0; ntl < 2; ++ntl) {
            int nt = wkey * 2 + ntl;
            int mval = mk[kt * 64 + nt * 16 + col];
            float fm = (mval == 0) ? -1e30f : 0.0f;
#pragma unroll
            for (int reg = 0; reg < 4; ++reg)
                bb[ntl][reg] = (brow[(size_t)reg * Lq + kt * 64 + nt * 16] + fm) * LOG2E;
        }
    };

    // K/V register staging: one 16B chunk per thread (512 chunks per tile)
    short8 kreg, vreg;
    auto loadKV = [&](int kt) {
        int row = tid >> 3, ch = tid & 7;
        kreg = *(const short8*)&K[(size_t)(kt * 64 + row) * HDq + ch * 8];
        vreg = *(const short8*)&V[(size_t)row * Lq + kt * 64 + ch * 8];
    };
    auto writeKV = [&](int buf) {
        int row = tid >> 3, ch = tid & 7;
        *(short8*)&Ks[buf][row][ch * 8] = kreg;
        *(short8*)&Vt[buf][row][ch * 8] = vreg;
    };

    float4v Oacc[2];
    float l_part[4];
#pragma unroll
    for (int ntl = 0; ntl < 2; ++ntl) Oacc[ntl] = (float4v){0.f, 0.f, 0.f, 0.f};
#pragma unroll
    for (int r = 0; r < 4; ++r) l_part[r] = 0.f;

    // prologue: tile 0 staged single-buffered
    loadKV(0);
    writeKV(0);
    prefetch(0, bcur);
    __syncthreads();

    int cur = 0;
    for (int kt = 0; kt < Lq / 64; ++kt) {
        const bool more = (kt + 1 < Lq / 64);
        if (more) {            // issue next tile's global loads NOW
            loadKV(kt + 1);
            prefetch(kt + 1, bnxt);
        }

        // --- QK^T: 16 rows x 32 keys (this wave's key half) ---
        float4v S[2];
#pragma unroll
        for (int ntl = 0; ntl < 2; ++ntl) S[ntl] = (float4v){0.f, 0.f, 0.f, 0.f};
        __builtin_amdgcn_s_setprio(1);
#pragma unroll
        for (int kk = 0; kk < 2; ++kk) {
#pragma unroll
            for (int ntl = 0; ntl < 2; ++ntl) {
                short8 bfr = *(const short8*)
                    &Ks[cur][(wkey * 2 + ntl) * 16 + col][kk * 32 + quad * 8];
                S[ntl] = __builtin_amdgcn_mfma_f32_16x16x32_bf16(qa[kk], bfr, S[ntl], 0, 0, 0);
            }
        }
        __builtin_amdgcn_s_setprio(0);

        // --- no-max softmax on this key half; deferred row-sum ---
#pragma unroll
        for (int ntl = 0; ntl < 2; ++ntl)
#pragma unroll
            for (int reg = 0; reg < 4; ++reg) {
                float p = __builtin_amdgcn_exp2f(
                    __builtin_fmaf(S[ntl][reg], LOG2E, bcur[ntl][reg]));
                l_part[reg] += p;
                Ps[wrow * 16 + quad * 4 + reg][(wkey * 2 + ntl) * 16 + col] = f2bf(p);
            }
        __syncthreads();   // P visible across sibling waves

        // --- PV: all 64 keys x this wave's 32 d-columns ---
        __builtin_amdgcn_s_setprio(1);
#pragma unroll
        for (int kk = 0; kk < 2; ++kk) {
            short8 pa = *(const short8*)&Ps[wrow * 16 + col][kk * 32 + quad * 8];
#pragma unroll
            for (int ntl = 0; ntl < 2; ++ntl) {
                short8 vb = *(const short8*)
                    &Vt[cur][(wkey * 2 + ntl) * 16 + col][kk * 32 + quad * 8];
                Oacc[ntl] = __builtin_amdgcn_mfma_f32_16x16x32_bf16(pa, vb, Oacc[ntl], 0, 0, 0);
            }
        }
        __builtin_amdgcn_s_setprio(0);

        // --- write next tile into the other buffer (vmcnt wait on kreg/vreg) ---
        if (more) writeKV(cur ^ 1);
        __syncthreads();   // next buf visible; Ps/Ks/Vt[cur] reads done
        cur ^= 1;

#pragma unroll
        for (int ntl = 0; ntl < 2; ++ntl)
#pragma unroll
            for (int reg = 0; reg < 4; ++reg)
                bcur[ntl][reg] = bnxt[ntl][reg];
    }

    // --- epilogue: l = own-half sum + sibling-half sum, then AO bf16 ---
    float lown[4];
#pragma unroll
    for (int reg = 0; reg < 4; ++reg) {
        float v = l_part[reg];
#pragma unroll
        for (int off = 1; off < 16; off <<= 1)
            v += __shfl_xor(v, off, 64);
        lown[reg] = v;
    }
    if (col == 0) {
#pragma unroll
        for (int reg = 0; reg < 4; ++reg)
            lbuf[wave][quad * 4 + reg] = lown[reg];
    }
    __syncthreads();

    short* aorow = AO + ((size_t)b * Lq + qt * 64 + wrow * 16 + quad * 4) * DIMq
                 + h * HDq + wkey * 32 + col;
#pragma unroll
    for (int reg = 0; reg < 4; ++reg) {
        float inv = 1.0f / (lown[reg] + lbuf[wave ^ 1][quad * 4 + reg]);
#pragma unroll
        for (int ntl = 0; ntl < 2; ++ntl)
            aorow[(size_t)reg * DIMq + 16 * ntl] = f2bf(Oacc[ntl][reg] * inv);
    }
}

// ---------------------------------------------------------------------------
extern "C" void kernel_launch(void* const* d_in, const int* in_sizes, int n_in,
                              void* d_out, int out_size, void* d_ws, size_t ws_size,
                              hipStream_t stream) {
    const float* x        = (const float*)d_in[0];
    const float* pos_bias = (const float*)d_in[1];
    const float* Wq       = (const float*)d_in[2];
    const float* Wk       = (const float*)d_in[3];
    const float* Wv       = (const float*)d_in[4];
    const float* Wo       = (const float*)d_in[5];
    const int*   mask     = (const int*)d_in[6];
    float* out = (float*)d_out;

    const size_t nX = (size_t)Bq * Lq * DIMq;       // 3,145,728
    const size_t nW = (size_t)DIMq * DIMq;          //   589,824
    short* xb  = (short*)d_ws;
    short* wqb = xb  + nX;
    short* wkb = wqb + nW;
    short* wvb = wkb + nW;
    short* wob = wvb + nW;
    short* Qh  = wob + nW;
    short* Kh  = Qh  + nX;
    short* Vh  = Kh  + nX;
    short* AOb = Vh  + nX;
    short* VTb = xb;   // xb is dead after the QKV GEMM; reuse for V^T

    dim3 blk(256);
    hipLaunchKernelGGL(to_bf16, dim3(1344), blk, 0, stream,
                       x, Wq, Wk, Wv, Wo, xb, wqb, wkb, wvb, wob);

    // fused QKV projections, 128x128 tiles
    hipLaunchKernelGGL(gemm_bf16, dim3(DIMq / 128, (Bq * Lq) / 128, 3), blk, 0, stream,
                       xb, wqb, wkb, wvb, Qh, Kh, Vh, (float*)nullptr, 1);

    // V: [B][NH][L][HD] -> [B][NH][HD][L]
    hipLaunchKernelGGL(transpose_v, dim3(Lq / 64, Bq * NHq), blk, 0, stream,
                       Vh, VTb);

    hipLaunchKernelGGL(attn_fwd_mfma, dim3(Lq / 64 * NHq * Bq), dim3(512), 0, stream,
                       Qh, Kh, VTb, pos_bias, mask, AOb);

    // output projection, fp32 out
    hipLaunchKernelGGL(gemm_bf16, dim3(DIMq / 128, (Bq * Lq) / 128, 1), blk, 0, stream,
                       AOb, wob, wob, wob, (short*)nullptr, (short*)nullptr,
                       (short*)nullptr, out, 0);
}

// Round 8
// 382.425 us; speedup vs baseline: 1.0470x; 1.0045x over previous
//
#include <hip/hip_runtime.h>
#include <math.h>

#define Bq 2
#define Lq 2048
#define DIMq 768
#define NHq 12
#define HDq 64
#define LOG2E 1.44269504f

typedef __attribute__((ext_vector_type(8))) short short8;
typedef __attribute__((ext_vector_type(4))) short short4v;
typedef __attribute__((ext_vector_type(4))) float float4v;

typedef __attribute__((address_space(3))) unsigned int as3_u32;
typedef __attribute__((address_space(1))) unsigned int as1_u32;

static __device__ __forceinline__ short f2bf(float f) {
    union { float f; unsigned u; } v; v.f = f;
    unsigned r = (v.u + 0x7FFF + ((v.u >> 16) & 1)) >> 16;   // RNE
    return (short)r;
}

// async global->LDS, 16B per lane (wave-uniform LDS base + lane*16)
static __device__ __forceinline__ void gld_lds16(const short* g, short* l) {
    __builtin_amdgcn_global_load_lds((const as1_u32*)g, (as3_u32*)l, 16, 0, 0);
}

// ---------------------------------------------------------------------------
// fp32 -> bf16 conversion for x and the four weight matrices.
// ---------------------------------------------------------------------------
__global__ __launch_bounds__(256)
void to_bf16(const float* __restrict__ x,  const float* __restrict__ wq,
             const float* __restrict__ wk, const float* __restrict__ wv,
             const float* __restrict__ wo,
             short* __restrict__ xb, short* __restrict__ wqb,
             short* __restrict__ wkb, short* __restrict__ wvb,
             short* __restrict__ wob)
{
    int blk = blockIdx.x;
    const float* s; short* d; int off;
    if      (blk <  768) { s = x;  d = xb;  off = blk * 1024; }
    else if (blk <  912) { s = wq; d = wqb; off = (blk -  768) * 1024; }
    else if (blk < 1056) { s = wk; d = wkb; off = (blk -  912) * 1024; }
    else if (blk < 1200) { s = wv; d = wvb; off = (blk - 1056) * 1024; }
    else                 { s = wo; d = wob; off = (blk - 1200) * 1024; }
    const float4* s4 = (const float4*)s;
    short4v* d4 = (short4v*)d;
#pragma unroll
    for (int i = 0; i < 4; ++i) {
        int idx = off + threadIdx.x + i * 256;
        float4 v = s4[idx];
        short4v o;
        o[0] = f2bf(v.x); o[1] = f2bf(v.y); o[2] = f2bf(v.z); o[3] = f2bf(v.w);
        d4[idx] = o;
    }
}

// ---------------------------------------------------------------------------
// bf16 MFMA GEMM, templated tile 128xBN (BN = 128 or 64), BK=64, 256 thr =
// 4 waves in 2x2; wave computes 64 x BN/2 via 4 x BN/32 16x16x32 frags.
// __launch_bounds__(256,3): VGPR<=170 -> 3 blocks/CU (QKV's 576 blocks all
// co-resident in ONE pass; was 2/CU = 512+64-block tail pass).
// BN=64 for the out-projection: grid 12x32=384 blocks -> all 256 CUs busy
// (was 6x32=192 blocks -> 64 CUs idle).
// mode 1: write bf16 split-head [B][NH][L][HD]; mode 0: fp32 flat [M][768].
// ---------------------------------------------------------------------------
template<int BN>
__global__ __launch_bounds__(256, 3)
void gemm_bf16(const short* __restrict__ A,
               const short* __restrict__ W0, const short* __restrict__ W1,
               const short* __restrict__ W2,
               short* __restrict__ D0, short* __restrict__ D1,
               short* __restrict__ D2, float* __restrict__ DF, int mode)
{
    constexpr int NT = BN / 32;            // frags per wave in n
    const int z = blockIdx.z;
    const short* W = (z == 0) ? W0 : ((z == 1) ? W1 : W2);
    short* DH = (z == 0) ? D0 : ((z == 1) ? D1 : D2);

    __shared__ __align__(16) short As[128][64];   // linear: global_load_lds dst
    __shared__ __align__(16) short Ws[BN][64];

    const int tid  = threadIdx.x;
    const int wave = tid >> 6;
    const int lane = tid & 63;
    const int col  = lane & 15;
    const int quad = lane >> 4;
    const int wr = wave >> 1, wc = wave & 1;
    const int m0 = blockIdx.y * 128, n0 = blockIdx.x * BN;

    float4v acc[4][NT];
#pragma unroll
    for (int mt = 0; mt < 4; ++mt)
#pragma unroll
        for (int nt = 0; nt < NT; ++nt) acc[mt][nt] = (float4v){0.f, 0.f, 0.f, 0.f};

    const short* Ab = A + (size_t)m0 * DIMq;
    const short* Wb = W + (size_t)n0 * DIMq;

    for (int k0 = 0; k0 < DIMq; k0 += 64) {
        __syncthreads();                       // readers done with LDS
        // A: 128 rows x 64 cols x 2B = 1024 chunks of 16B; W: BN*8 chunks
#pragma unroll
        for (int i = 0; i < 4; ++i) {
            int g = i * 256 + tid;
            int row = g >> 3, ch = g & 7;
            gld_lds16(Ab + (size_t)row * DIMq + k0 + ch * 8, (short*)As + g * 8);
        }
#pragma unroll
        for (int i = 0; i < BN / 32; ++i) {
            int g = i * 256 + tid;
            int row = g >> 3, ch = g & 7;
            gld_lds16(Wb + (size_t)row * DIMq + k0 + ch * 8, (short*)Ws + g * 8);
        }
        __syncthreads();                       // (compiler drains vmcnt here)
#pragma unroll
        for (int kk = 0; kk < 2; ++kk) {
            short8 a[4], bfr[NT];
#pragma unroll
            for (int mt = 0; mt < 4; ++mt)
                a[mt] = *(const short8*)&As[wr * 64 + mt * 16 + col][kk * 32 + quad * 8];
#pragma unroll
            for (int nt = 0; nt < NT; ++nt)
                bfr[nt] = *(const short8*)&Ws[wc * (BN / 2) + nt * 16 + col][kk * 32 + quad * 8];
#pragma unroll
            for (int mt = 0; mt < 4; ++mt)
#pragma unroll
                for (int nt = 0; nt < NT; ++nt)
                    acc[mt][nt] = __builtin_amdgcn_mfma_f32_16x16x32_bf16(
                        a[mt], bfr[nt], acc[mt][nt], 0, 0, 0);
        }
    }

#pragma unroll
    for (int mt = 0; mt < 4; ++mt)
#pragma unroll
    for (int reg = 0; reg < 4; ++reg) {
        int m = m0 + wr * 64 + mt * 16 + quad * 4 + reg;
#pragma unroll
        for (int nt = 0; nt < NT; ++nt) {
            int n = n0 + wc * (BN / 2) + nt * 16 + col;
            if (mode == 1) {
                int b = m >> 11, l = m & 2047, h = n >> 6, c = n & 63;
                DH[(((size_t)(b * NHq + h)) * Lq + l) * HDq + c] = f2bf(acc[mt][nt][reg]);
            } else {
                DF[(size_t)m * DIMq + n] = acc[mt][nt][reg];
            }
        }
    }
}

// ---------------------------------------------------------------------------
// V transpose: [B][NH][L][HD] -> [B][NH][HD][L], once.
// ---------------------------------------------------------------------------
__global__ __launch_bounds__(256)
void transpose_v(const short* __restrict__ Vh, short* __restrict__ VT)
{
    const int lt = blockIdx.x;   // 0..31 (64-row L tile)
    const int bh = blockIdx.y;   // 0..23 (b*NH+h)
    const short* src = Vh + ((size_t)bh * Lq + lt * 64) * HDq;
    short* dst = VT + (size_t)bh * HDq * Lq + lt * 64;
    __shared__ __align__(16) short t[64][72];
    const int tid = threadIdx.x;
    {
        int row = tid & 63, seg = tid >> 6;          // seg: 16-col chunk
        *(short8*)&t[row][seg * 16]     = *(const short8*)&src[row * HDq + seg * 16];
        *(short8*)&t[row][seg * 16 + 8] = *(const short8*)&src[row * HDq + seg * 16 + 8];
    }
    __syncthreads();
    {
        int c = tid >> 2, seg = tid & 3;             // c: hd row, seg: 16-l chunk
        short8 o0, o1;
#pragma unroll
        for (int j = 0; j < 8; ++j) o0[j] = t[seg * 16 + j][c];
#pragma unroll
        for (int j = 0; j < 8; ++j) o1[j] = t[seg * 16 + 8 + j][c];
        *(short8*)&dst[(size_t)c * Lq + seg * 16]     = o0;
        *(short8*)&dst[(size_t)c * Lq + seg * 16 + 8] = o1;
    }
}

// ---------------------------------------------------------------------------
// MFMA flash attention, no-max softmax, 8-wave key-split blocks (512 thr).
// (unchanged from round 6 to isolate the GEMM delta)
// ---------------------------------------------------------------------------
__global__ __launch_bounds__(512, 6)
void attn_fwd_mfma(const short* __restrict__ Qh, const short* __restrict__ Kh,
                   const short* __restrict__ VT, const float* __restrict__ pos_bias,
                   const int* __restrict__ mask, short* __restrict__ AO)
{
    // hw block -> XCD chunk of 96 consecutive logicals; logical = (h*32+qt)*2+b
    const int hw = blockIdx.x;                     // 0..767
    const int logical = (hw & 7) * 96 + (hw >> 3);
    const int b  = logical & 1;
    const int qt = (logical >> 1) & 31;
    const int h  = logical >> 6;

    const short* Q = Qh + ((size_t)(b * NHq + h)) * Lq * HDq;
    const short* K = Kh + ((size_t)(b * NHq + h)) * Lq * HDq;
    const short* V = VT + ((size_t)(b * NHq + h)) * HDq * Lq;   // [hd][L]
    const int* mk = mask + (size_t)b * Lq;

    __shared__ __align__(16) short Ks[2][64][72];  // [buf][key][hd]
    __shared__ __align__(16) short Vt[2][64][72];  // [buf][hd][key]
    __shared__ __align__(16) short Ps[64][72];     // [qrow][key]
    __shared__ float lbuf[8][16];                  // per-wave row l partials

    const int tid  = threadIdx.x;
    const int wave = tid >> 6;        // 0..7
    const int lane = tid & 63;
    const int col  = lane & 15;
    const int quad = lane >> 4;
    const int wrow = wave >> 1;       // 0..3: q-row band
    const int wkey = wave & 1;        // 0..1: key/d half

    // persistent Q A-frags (rows wrow*16 + col)
    short8 qa[2];
    {
        const short* qrow = Q + (size_t)(qt * 64 + wrow * 16 + col) * HDq;
        qa[0] = *(const short8*)&qrow[quad * 8];
        qa[1] = *(const short8*)&qrow[32 + quad * 8];
    }

    const float* brow = pos_bias + (size_t)h * Lq * Lq
                      + (size_t)(qt * 64 + wrow * 16 + quad * 4) * Lq + col;

    float bcur[2][4], bnxt[2][4];
    auto prefetch = [&](int kt, float (&bb)[2][4]) {
#pragma unroll
        for (int ntl = 0; ntl < 2; ++ntl) {
            int nt = wkey * 2 + ntl;
            int mval = mk[kt * 64 + nt * 16 + col];
            float fm = (mval == 0) ? -1e30f : 0.0f;
#pragma unroll
            for (int reg = 0; reg < 4; ++reg)
                bb[ntl][reg] = (brow[(size_t)reg * Lq + kt * 64 + nt * 16] + fm) * LOG2E;
        }
    };

    // K/V register staging: one 16B chunk per thread (512 chunks per tile)
    short8 kreg, vreg;
    auto loadKV = [&](int kt) {
        int row = tid >> 3, ch = tid & 7;
        kreg = *(const short8*)&K[(size_t)(kt * 64 + row) * HDq + ch * 8];
        vreg = *(const short8*)&V[(size_t)row * Lq + kt * 64 + ch * 8];
    };
    auto writeKV = [&](int buf) {
        int row = tid >> 3, ch = tid & 7;
        *(short8*)&Ks[buf][row][ch * 8] = kreg;
        *(short8*)&Vt[buf][row][ch * 8] = vreg;
    };

    float4v Oacc[2];
    float l_part[4];
#pragma unroll
    for (int ntl = 0; ntl < 2; ++ntl) Oacc[ntl] = (float4v){0.f, 0.f, 0.f, 0.f};
#pragma unroll
    for (int r = 0; r < 4; ++r) l_part[r] = 0.f;

    // prologue: tile 0 staged single-buffered
    loadKV(0);
    writeKV(0);
    prefetch(0, bcur);
    __syncthreads();

    int cur = 0;
    for (int kt = 0; kt < Lq / 64; ++kt) {
        const bool more = (kt + 1 < Lq / 64);
        if (more) {            // issue next tile's global loads NOW
            loadKV(kt + 1);
            prefetch(kt + 1, bnxt);
        }

        // --- QK^T: 16 rows x 32 keys (this wave's key half) ---
        float4v S[2];
#pragma unroll
        for (int ntl = 0; ntl < 2; ++ntl) S[ntl] = (float4v){0.f, 0.f, 0.f, 0.f};
        __builtin_amdgcn_s_setprio(1);
#pragma unroll
        for (int kk = 0; kk < 2; ++kk) {
#pragma unroll
            for (int ntl = 0; ntl < 2; ++ntl) {
                short8 bfr = *(const short8*)
                    &Ks[cur][(wkey * 2 + ntl) * 16 + col][kk * 32 + quad * 8];
                S[ntl] = __builtin_amdgcn_mfma_f32_16x16x32_bf16(qa[kk], bfr, S[ntl], 0, 0, 0);
            }
        }
        __builtin_amdgcn_s_setprio(0);

        // --- no-max softmax on this key half; deferred row-sum ---
#pragma unroll
        for (int ntl = 0; ntl < 2; ++ntl)
#pragma unroll
            for (int reg = 0; reg < 4; ++reg) {
                float p = __builtin_amdgcn_exp2f(
                    __builtin_fmaf(S[ntl][reg], LOG2E, bcur[ntl][reg]));
                l_part[reg] += p;
                Ps[wrow * 16 + quad * 4 + reg][(wkey * 2 + ntl) * 16 + col] = f2bf(p);
            }
        __syncthreads();   // P visible across sibling waves

        // --- PV: all 64 keys x this wave's 32 d-columns ---
        __builtin_amdgcn_s_setprio(1);
#pragma unroll
        for (int kk = 0; kk < 2; ++kk) {
            short8 pa = *(const short8*)&Ps[wrow * 16 + col][kk * 32 + quad * 8];
#pragma unroll
            for (int ntl = 0; ntl < 2; ++ntl) {
                short8 vb = *(const short8*)
                    &Vt[cur][(wkey * 2 + ntl) * 16 + col][kk * 32 + quad * 8];
                Oacc[ntl] = __builtin_amdgcn_mfma_f32_16x16x32_bf16(pa, vb, Oacc[ntl], 0, 0, 0);
            }
        }
        __builtin_amdgcn_s_setprio(0);

        // --- write next tile into the other buffer (vmcnt wait on kreg/vreg) ---
        if (more) writeKV(cur ^ 1);
        __syncthreads();   // next buf visible; Ps/Ks/Vt[cur] reads done
        cur ^= 1;

#pragma unroll
        for (int ntl = 0; ntl < 2; ++ntl)
#pragma unroll
            for (int reg = 0; reg < 4; ++reg)
                bcur[ntl][reg] = bnxt[ntl][reg];
    }

    // --- epilogue: l = own-half sum + sibling-half sum, then AO bf16 ---
    float lown[4];
#pragma unroll
    for (int reg = 0; reg < 4; ++reg) {
        float v = l_part[reg];
#pragma unroll
        for (int off = 1; off < 16; off <<= 1)
            v += __shfl_xor(v, off, 64);
        lown[reg] = v;
    }
    if (col == 0) {
#pragma unroll
        for (int reg = 0; reg < 4; ++reg)
            lbuf[wave][quad * 4 + reg] = lown[reg];
    }
    __syncthreads();

    short* aorow = AO + ((size_t)b * Lq + qt * 64 + wrow * 16 + quad * 4) * DIMq
                 + h * HDq + wkey * 32 + col;
#pragma unroll
    for (int reg = 0; reg < 4; ++reg) {
        float inv = 1.0f / (lown[reg] + lbuf[wave ^ 1][quad * 4 + reg]);
#pragma unroll
        for (int ntl = 0; ntl < 2; ++ntl)
            aorow[(size_t)reg * DIMq + 16 * ntl] = f2bf(Oacc[ntl][reg] * inv);
    }
}

// ---------------------------------------------------------------------------
extern "C" void kernel_launch(void* const* d_in, const int* in_sizes, int n_in,
                              void* d_out, int out_size, void* d_ws, size_t ws_size,
                              hipStream_t stream) {
    const float* x        = (const float*)d_in[0];
    const float* pos_bias = (const float*)d_in[1];
    const float* Wq       = (const float*)d_in[2];
    const float* Wk       = (const float*)d_in[3];
    const float* Wv       = (const float*)d_in[4];
    const float* Wo       = (const float*)d_in[5];
    const int*   mask     = (const int*)d_in[6];
    float* out = (float*)d_out;

    const size_t nX = (size_t)Bq * Lq * DIMq;       // 3,145,728
    const size_t nW = (size_t)DIMq * DIMq;          //   589,824
    short* xb  = (short*)d_ws;
    short* wqb = xb  + nX;
    short* wkb = wqb + nW;
    short* wvb = wkb + nW;
    short* wob = wvb + nW;
    short* Qh  = wob + nW;
    short* Kh  = Qh  + nX;
    short* Vh  = Kh  + nX;
    short* AOb = Vh  + nX;
    short* VTb = xb;   // xb is dead after the QKV GEMM; reuse for V^T

    dim3 blk(256);
    hipLaunchKernelGGL(to_bf16, dim3(1344), blk, 0, stream,
                       x, Wq, Wk, Wv, Wo, xb, wqb, wkb, wvb, wob);

    // fused QKV projections, 128x128 tiles, 3 blocks/CU single pass
    hipLaunchKernelGGL((gemm_bf16<128>), dim3(DIMq / 128, (Bq * Lq) / 128, 3), blk, 0, stream,
                       xb, wqb, wkb, wvb, Qh, Kh, Vh, (float*)nullptr, 1);

    // V: [B][NH][L][HD] -> [B][NH][HD][L]
    hipLaunchKernelGGL(transpose_v, dim3(Lq / 64, Bq * NHq), blk, 0, stream,
                       Vh, VTb);

    hipLaunchKernelGGL(attn_fwd_mfma, dim3(Lq / 64 * NHq * Bq), dim3(512), 0, stream,
                       Qh, Kh, VTb, pos_bias, mask, AOb);

    // output projection, 128x64 tiles -> 384 blocks (all CUs busy), fp32 out
    hipLaunchKernelGGL((gemm_bf16<64>), dim3(DIMq / 64, (Bq * Lq) / 128, 1), blk, 0, stream,
                       AOb, wob, wob, wob, (short*)nullptr, (short*)nullptr,
                       (short*)nullptr, out, 0);
}